// Round 1
// 5612.417 us; speedup vs baseline: 1.3478x; 1.3478x over previous
//
#include <hip/hip_runtime.h>
#include <float.h>
#include <math.h>

#define B_    128
#define H_    512
#define V_    1000
#define T_    256
#define G4_   2048
#define NBLK  256     // cooperative launch limit: 1 block/CU

#define AT_LOAD(p)    __hip_atomic_load((p), __ATOMIC_RELAXED, __HIP_MEMORY_SCOPE_AGENT)
#define AT_STORE(p,v) __hip_atomic_store((p), (v), __ATOMIC_RELAXED, __HIP_MEMORY_SCOPE_AGENT)

// LDS h-row swizzle: logical float col c (0..511) -> physical col.
// Within each 32-float chunk, quad index is XOR'd with (chunk&7) so that
// lanes reading "logical quad j of chunk kc" simultaneously hit distinct
// bank groups (2-way max = free).  Weights stay in logical order; only the
// LDS write (staging) and LDS read addresses carry the XOR.
__device__ __forceinline__ int swz(int c) {
  const int j4  = (c >> 2) & 7;
  const int ch7 = (c >> 5) & 7;
  return (c & ~28) | ((j4 ^ ch7) << 2);
}

__device__ __forceinline__ float dot4(float4 a, float4 b, float acc) {
  return fmaf(a.x, b.x, fmaf(a.y, b.y, fmaf(a.z, b.z, fmaf(a.w, b.w, acc))));
}

// ---------------------------------------------------------------------------
// Precompute GEMM:  C[M][N] = A[M][0:512] * Bm[N][koff:koff+512]^T (+bias1+bias2)
// ---------------------------------------------------------------------------
__global__ __launch_bounds__(256) void gemm_nt_k512(
    const float* __restrict__ A, int M,
    const float* __restrict__ Bm, int ldb, int koff,
    const float* __restrict__ bias1, const float* __restrict__ bias2,
    float* __restrict__ C, int ldc)
{
  __shared__ float As[16][68];
  __shared__ float Bs[16][68];
  const int tid = threadIdx.x;
  const int m0 = blockIdx.y * 64, n0 = blockIdx.x * 64;
  const int tm = tid & 15, tn = tid >> 4;
  const int lm = tid & 63, kq = tid >> 6;
  float acc[4][4] = {};
  for (int k0 = 0; k0 < 512; k0 += 16) {
    float4 av = make_float4(0.f, 0.f, 0.f, 0.f);
    if (m0 + lm < M) av = *(const float4*)(A + (size_t)(m0 + lm) * 512 + k0 + kq * 4);
    float4 bv = *(const float4*)(Bm + (size_t)(n0 + lm) * ldb + koff + k0 + kq * 4);
    __syncthreads();
    As[kq*4+0][lm] = av.x; As[kq*4+1][lm] = av.y; As[kq*4+2][lm] = av.z; As[kq*4+3][lm] = av.w;
    Bs[kq*4+0][lm] = bv.x; Bs[kq*4+1][lm] = bv.y; Bs[kq*4+2][lm] = bv.z; Bs[kq*4+3][lm] = bv.w;
    __syncthreads();
#pragma unroll
    for (int kk = 0; kk < 16; ++kk) {
      const float4 a = *(const float4*)&As[kk][tm * 4];
      const float4 b = *(const float4*)&Bs[kk][tn * 4];
      const float aa[4] = {a.x, a.y, a.z, a.w};
      const float bb[4] = {b.x, b.y, b.z, b.w};
#pragma unroll
      for (int i = 0; i < 4; ++i)
#pragma unroll
        for (int j = 0; j < 4; ++j)
          acc[i][j] = fmaf(aa[i], bb[j], acc[i][j]);
    }
  }
#pragma unroll
  for (int i = 0; i < 4; ++i) {
    const int m = m0 + tm * 4 + i;
    if (m < M) {
#pragma unroll
      for (int j = 0; j < 4; ++j) {
        const int n = n0 + tn * 4 + j;
        float v = acc[i][j];
        if (bias1) v += bias1[n];
        if (bias2) v += bias2[n];
        C[(size_t)m * ldc + n] = v;
      }
    }
  }
}

// ---------------------------------------------------------------------------
// amax word: [val:f32 bits in high 32][tag:16][token:16]; tag(t) = t+2.
// ---------------------------------------------------------------------------
__global__ __launch_bounds__(256) void init_kernel(
    const float* __restrict__ ctx, float* __restrict__ hbuf,
    unsigned long long* __restrict__ amax,
    int* __restrict__ hdone, const int* __restrict__ start_id)
{
  const int i = blockIdx.x * blockDim.x + threadIdx.x;
  // h(-1) = context into slot 1
  ((float4*)(hbuf + B_ * H_))[i] = ((const float4*)ctx)[i];
  if (i < B_ * 32) {
    const int m = i & 31;
    const unsigned long long w = (m == 0)
        ? ((((unsigned long long)__float_as_uint(FLT_MAX)) << 32) |
           (1u << 16) | (unsigned)(*start_id))
        : ((((unsigned long long)__float_as_uint(-FLT_MAX)) << 32) | (1u << 16));
    amax[(size_t)B_ * 32 + i] = w;   // parity-1 slot, tag(-1)=1
  }
  if (i < 2 * 8 * 32) hdone[i * 16] = 0;
}

// ---------------------------------------------------------------------------
// Persistent cooperative decoder, 1024 threads/block.
// 8 groups x 32 blocks; group g owns rows [16g,16g+16).  Tagged-dataflow
// sync (no grid barriers).
//
// NEW vs previous round:
//  * Whh/Wout weight slices live in REGISTERS (loaded once): phase-1 lane
//    owns (gate-line, K-chunk of 32) -> 8 float4; phase-2 lane owns
//    (vocab, K-chunk of 16) -> 4 float4.  Cross-lane K combine via
//    shfl_xor (width 16 / width 32).  Removes ~192 KB/block/step of L2
//    weight traffic whose latency dominated the 31 us step time.
//  * h staged into LDS with per-chunk XOR swizzle (see swz()) so the
//    K-split reads are bank-conflict-free-ish.
//  * Phase-1 GEMM (token-independent) runs BEFORE the amax poll; the
//    proj[token] term is added afterwards by a 1024-thread pass.  Hides
//    the argmax round-trip under the big GEMM.
// ---------------------------------------------------------------------------
__global__ __launch_bounds__(1024) void decoder_main(
    const float* __restrict__ Whh,
    const float* __restrict__ Wout,
    const float* __restrict__ bout,
    const float* __restrict__ proj,
    const float* __restrict__ basep,
    float* __restrict__ hbuf,
    unsigned long long* __restrict__ amax,
    int* __restrict__ hdone,
    float* __restrict__ out)
{
  __shared__ struct alignas(16) SM {
    float hs[16][512];          // h tile, swizzled (see swz)
    float gbase[16][64];        // basep slice, loaded once
    float gbuf[16][65];         // gate accumulators (stride 65: epilogue b128)
    float lbuf[16][33];         // logits partials for argmax
    int   tok[16];
  } sm;

  const int tid  = threadIdx.x;
  const int bid  = blockIdx.x;
  const int gid  = bid >> 5;     // group: rows [16g, 16g+16)
  const int mem  = bid & 31;     // member: units [16*mem,+16) / vocab [32*mem,+32)
  const int lane = tid & 63;
  const int w    = tid >> 6;     // wave 0..15
  const int row_base = gid * 16;
  const int vb   = mem * 32;

  // phase-1 lane constants: wave w quarter q1 owns gate-line 4w+q1; lane&15 = K-chunk
  const int q1  = lane >> 4;
  const int kc  = lane & 15;
  const int gl4 = (w << 2) | q1;            // 0..63
  const int u1 = gl4 & 15, g1 = gl4 >> 4;   // unit-in-slice, gate
  const int gidx = mem * 16 + u1 + g1 * 512;
  const int hb1 = kc * 32;                  // logical chunk base (floats)
  const int hx1 = (kc & 7) << 2;            // quad XOR for swizzled reads

  // phase-2 lane constants: lane>>5 = vocab sub, lane&31 = K-chunk of 16
  const int q2  = lane >> 5;
  const int kc5 = lane & 31;
  const int v2  = vb + w * 2 + q2;
  const int vclamp = (v2 < V_) ? v2 : 0;
  const int ch2 = kc5 >> 1;
  const int lj0 = (kc5 & 1) * 4;
  int o2[4];
#pragma unroll
  for (int j = 0; j < 4; ++j)
    o2[j] = ch2 * 32 + (((lj0 + j) ^ (ch2 & 7)) << 2);

  // ---- one-time preloads (weights -> registers, basep -> LDS) ------------
  float4 w1r[8];
  {
    const float* p = Whh + (size_t)gidx * H_ + hb1;
#pragma unroll
    for (int j = 0; j < 8; ++j) w1r[j] = *(const float4*)(p + j * 4);
  }
  float4 w2r[4];
  {
    const float* p = Wout + (size_t)vclamp * H_ + kc5 * 16;
#pragma unroll
    for (int j = 0; j < 4; ++j) w2r[j] = *(const float4*)(p + j * 4);
  }
  const float bout_r = (v2 < V_) ? bout[v2] : 0.f;
  {
    const int r = tid >> 6, c6 = tid & 63, u = c6 & 15, g = c6 >> 4;
    sm.gbase[r][u * 4 + g] =
        basep[(size_t)(row_base + r) * G4_ + mem * 16 + u + g * 512];
  }

  float c_reg = 0.f;   // tid<256 owns cell (row=row_base+(tid>>4), unit=mem*16+(tid&15))
  const size_t BTVo = (size_t)B_ * T_ * V_;
  __syncthreads();

  for (int t = 0; t < T_; ++t) {
    float* hdst = hbuf + (size_t)(t & 1) * (B_ * H_);

    // ---- t=0: stage context into hs (swizzled) -------------------------
    if (t == 0) {
      const float* hsrc = hbuf + (size_t)B_ * H_;   // slot 1 = context
      const unsigned long long* hq =
          (const unsigned long long*)(hsrc + (size_t)row_base * H_);
      unsigned long long v[4];
#pragma unroll
      for (int i = 0; i < 4; ++i)
        v[i] = AT_LOAD((unsigned long long*)&hq[tid + i * 1024]);
#pragma unroll
      for (int i = 0; i < 4; ++i) {
        const int idx = tid + i * 1024;
        *(unsigned long long*)&sm.hs[idx >> 8][swz((idx & 255) * 2)] = v[i];
      }
      __syncthreads();
    }

    // ---- A: phase-1 GEMM (token-independent), weights in registers -----
    {
#pragma unroll 1
      for (int r = 0; r < 16; ++r) {
        const float* hr = &sm.hs[r][hb1];
        const float4 h0 = *(const float4*)(hr + (0  ^ hx1));
        const float4 h1 = *(const float4*)(hr + (4  ^ hx1));
        const float4 h2 = *(const float4*)(hr + (8  ^ hx1));
        const float4 h3 = *(const float4*)(hr + (12 ^ hx1));
        const float4 h4 = *(const float4*)(hr + (16 ^ hx1));
        const float4 h5 = *(const float4*)(hr + (20 ^ hx1));
        const float4 h6 = *(const float4*)(hr + (24 ^ hx1));
        const float4 h7 = *(const float4*)(hr + (28 ^ hx1));
        float a0 = dot4(w1r[0], h0, 0.f);
        float a1 = dot4(w1r[1], h1, 0.f);
        float a2 = dot4(w1r[2], h2, 0.f);
        float a3 = dot4(w1r[3], h3, 0.f);
        a0 = dot4(w1r[4], h4, a0);
        a1 = dot4(w1r[5], h5, a1);
        a2 = dot4(w1r[6], h6, a2);
        a3 = dot4(w1r[7], h7, a3);
        float s = (a0 + a1) + (a2 + a3);
        s += __shfl_xor(s, 1, 16);
        s += __shfl_xor(s, 2, 16);
        s += __shfl_xor(s, 4, 16);
        s += __shfl_xor(s, 8, 16);
        if (kc == 0) sm.gbuf[r][u1 * 4 + g1] = s + sm.gbase[r][u1 * 4 + g1];
      }
    }

    // ---- B: poll amax(t-1) -> tok[] -------------------------------------
    if (tid < 512) {
      const int prow = tid >> 5, pj = tid & 31;
      const unsigned expect = (unsigned)(t + 1) << 16;   // tag(t-1) = t+1
      const unsigned long long* ap =
          amax + ((size_t)((t + 1) & 1) * B_ + row_base + prow) * 32;
      unsigned long long wv = AT_LOAD(&ap[pj]);
      while (((unsigned)wv ^ expect) & 0xFFFF0000u) {
        __builtin_amdgcn_s_sleep(1);
        wv = AT_LOAD(&ap[pj]);
      }
      __atomic_signal_fence(__ATOMIC_ACQ_REL);
      float v  = __uint_as_float((unsigned)(wv >> 32));
      int   ix = (int)((unsigned)wv & 0xFFFFu);
#pragma unroll
      for (int d = 16; d >= 1; d >>= 1) {
        const float vo = __shfl_xor(v, d, 32);
        const int   io = __shfl_xor(ix, d, 32);
        if (vo > v || (vo == v && io < ix)) { v = vo; ix = io; }
      }
      if (pj == 0) sm.tok[prow] = ix;
    }
    __syncthreads();

    // ---- C: add proj[token] into gbuf (one element per thread) ----------
    {
      const int r = tid >> 6, c6 = tid & 63, u = c6 & 15, g = c6 >> 4;
      const int tk = sm.tok[r];
      sm.gbuf[r][u * 4 + g] += proj[(size_t)tk * G4_ + mem * 16 + u + g * 512];
    }
    __syncthreads();

    // ---- D: LSTM epilogue (tid<256): c in register ----------------------
    if (tid < 256) {
      const int rl = tid >> 4, ul = tid & 15;
      const float4 g4 = *(const float4*)&sm.gbuf[rl][ul * 4];
      const float ig = 1.f / (1.f + expf(-g4.x));
      const float fg = 1.f / (1.f + expf(-g4.y));
      const float gg = tanhf(g4.z);
      const float og = 1.f / (1.f + expf(-g4.w));
      const float cn = fg * c_reg + ig * gg;
      c_reg = cn;
      const float hn = og * tanhf(cn);
      const int row = row_base + rl, hid = mem * 16 + ul;
      const float hn2 = __shfl_down(hn, 1);
      if ((ul & 1) == 0) {
        const unsigned long long pk =
            (unsigned long long)__float_as_uint(hn) |
            (((unsigned long long)__float_as_uint(hn2)) << 32);
        AT_STORE((unsigned long long*)&hdst[(size_t)row * H_ + hid], pk);
      }
      if (t == T_ - 1) {
        out[BTVo + (size_t)row * H_ + hid] = hn;                    // h_f
        out[BTVo + (size_t)B_ * H_ + (size_t)row * H_ + hid] = cn;  // c_f
      }
    }
    __syncthreads();   // drains vmcnt -> release for hdone flag
    if (tid == 0)
      AT_STORE(&hdone[(((t & 1) * 8 + gid) * 32 + mem) * 16], t + 2);

    // ---- E: wait for all members' h(t) ----------------------------------
    if (tid < 32) {
      int* fp = &hdone[(((t & 1) * 8 + gid) * 32 + tid) * 16];
      while (AT_LOAD(fp) != t + 2) __builtin_amdgcn_s_sleep(1);
    }
    __atomic_signal_fence(__ATOMIC_ACQ_REL);
    __syncthreads();

    // ---- F: stage h(t) into hs (swizzled) -------------------------------
    {
      const unsigned long long* hq =
          (const unsigned long long*)(hdst + (size_t)row_base * H_);
      unsigned long long v[4];
#pragma unroll
      for (int i = 0; i < 4; ++i)
        v[i] = AT_LOAD((unsigned long long*)&hq[tid + i * 1024]);
#pragma unroll
      for (int i = 0; i < 4; ++i) {
        const int idx = tid + i * 1024;
        *(unsigned long long*)&sm.hs[idx >> 8][swz((idx & 255) * 2)] = v[i];
      }
    }
    __syncthreads();

    // ---- G: logits GEMM, weights in registers ---------------------------
    {
#pragma unroll 2
      for (int r = 0; r < 16; ++r) {
        const float* hr = sm.hs[r];
        const float4 h0 = *(const float4*)(hr + o2[0]);
        const float4 h1 = *(const float4*)(hr + o2[1]);
        const float4 h2 = *(const float4*)(hr + o2[2]);
        const float4 h3 = *(const float4*)(hr + o2[3]);
        float a0 = dot4(w2r[0], h0, 0.f);
        float a1 = dot4(w2r[1], h1, 0.f);
        float a2 = dot4(w2r[2], h2, 0.f);
        float a3 = dot4(w2r[3], h3, 0.f);
        float s = (a0 + a1) + (a2 + a3);
        s += __shfl_xor(s, 1, 32);
        s += __shfl_xor(s, 2, 32);
        s += __shfl_xor(s, 4, 32);
        s += __shfl_xor(s, 8, 32);
        s += __shfl_xor(s, 16, 32);
        if (kc5 == 0) {
          if (v2 < V_) {
            const float sv = s + bout_r;
            out[((size_t)(row_base + r) * T_ + t) * V_ + v2] = sv;
            sm.lbuf[r][w * 2 + q2] = sv;
          } else {
            sm.lbuf[r][w * 2 + q2] = -FLT_MAX;
          }
        }
      }
    }
    __syncthreads();

    // ---- H: per-member argmax partial -----------------------------------
    if (tid < 512) {
      const int r = tid >> 5, j = tid & 31;
      float v = sm.lbuf[r][j];
      int ix = j;
#pragma unroll
      for (int d = 16; d >= 1; d >>= 1) {
        const float vo = __shfl_xor(v, d, 32);
        const int   io = __shfl_xor(ix, d, 32);
        if (vo > v || (vo == v && io < ix)) { v = vo; ix = io; }
      }
      if (j == 0) {
        const unsigned long long pk =
            (((unsigned long long)__float_as_uint(v)) << 32) |
            ((unsigned)(t + 2) << 16) | (unsigned)(vb + ix);
        AT_STORE(&amax[((size_t)(t & 1) * B_ + row_base + r) * 32 + mem], pk);
      }
    }
    // no barrier: loop back to next step (hs untouched until F of next iter)
  }
}

// ---------------------------------------------------------------------------
extern "C" void kernel_launch(void* const* d_in, const int* in_sizes, int n_in,
                              void* d_out, int out_size, void* d_ws, size_t ws_size,
                              hipStream_t stream)
{
  const float* ctx   = (const float*)d_in[0];
  const float* emb   = (const float*)d_in[1];
  const float* Wih   = (const float*)d_in[2];
  const float* bih   = (const float*)d_in[3];
  const float* Whh   = (const float*)d_in[4];
  const float* bhh   = (const float*)d_in[5];
  const float* Wout  = (const float*)d_in[6];
  const float* bout  = (const float*)d_in[7];
  const int*   start = (const int*)d_in[8];
  float* out = (float*)d_out;

  // workspace layout (bytes)
  char* ws = (char*)d_ws;
  float* proj  = (float*)(ws + 0);                    // 1000*2048*4 = 8,192,000
  float* basep = (float*)(ws + 8192000);              // 128*2048*4  = 1,048,576
  float* hbuf  = (float*)(ws + 9240576);              // 2*128*512*4 =   524,288
  unsigned long long* amax = (unsigned long long*)(ws + 9764864);  // 2*128*32*8 = 65,536
  int*   hdone = (int*)(ws + 9830400);                // 2*8*32*64B  =    32,768

  hipLaunchKernelGGL(gemm_nt_k512, dim3(32, 2), dim3(256), 0, stream,
                     ctx, B_, Wih, 1024, 0, bih, bhh, basep, G4_);
  hipLaunchKernelGGL(gemm_nt_k512, dim3(32, 16), dim3(256), 0, stream,
                     emb, V_, Wih, 1024, 512, (const float*)nullptr, (const float*)nullptr,
                     proj, G4_);
  hipLaunchKernelGGL(init_kernel, dim3(64), dim3(256), 0, stream,
                     ctx, hbuf, amax, hdone, start);

  void* args[] = {(void*)&Whh, (void*)&Wout, (void*)&bout, (void*)&proj, (void*)&basep,
                  (void*)&hbuf, (void*)&amax, (void*)&hdone, (void*)&out};
  hipLaunchCooperativeKernel(reinterpret_cast<const void*>(decoder_main),
                             dim3(NBLK), dim3(1024), args, 0, stream);
}

// Round 4
// 4291.764 us; speedup vs baseline: 1.7625x; 1.3077x over previous
//
#include <hip/hip_runtime.h>
#include <float.h>
#include <math.h>

#define B_    128
#define H_    512
#define V_    1000
#define T_    256
#define G4_   2048
#define NBLK  256          // cooperative launch: 1 block/CU
#define SPIN_MAX (1 << 17) // bounded spin: ~13ms worst-case, >> any legit wait

#define AT_LOAD(p)    __hip_atomic_load((p), __ATOMIC_RELAXED, __HIP_MEMORY_SCOPE_AGENT)
#define AT_STORE(p,v) __hip_atomic_store((p), (v), __ATOMIC_RELAXED, __HIP_MEMORY_SCOPE_AGENT)

__device__ __forceinline__ float dot4(float4 a, float4 b, float acc) {
  return fmaf(a.x, b.x, fmaf(a.y, b.y, fmaf(a.z, b.z, fmaf(a.w, b.w, acc))));
}

// 16-lane butterfly sum, pure DPP (VALU pipe, zero LDS traffic):
// xor1 = quad_perm[1,0,3,2] (0xB1), xor2 = quad_perm[2,3,0,1] (0x4E),
// xor7 = row_half_mirror (0x141), xor15 = row_mirror (0x140).
// Masks {1,2,7,15} generate GF(2)^4 -> full sum in every lane of each 16-row.
__device__ __forceinline__ float red16(float x) {
  x += __int_as_float(__builtin_amdgcn_mov_dpp(__float_as_int(x), 0xB1,  0xF, 0xF, true));
  x += __int_as_float(__builtin_amdgcn_mov_dpp(__float_as_int(x), 0x4E,  0xF, 0xF, true));
  x += __int_as_float(__builtin_amdgcn_mov_dpp(__float_as_int(x), 0x141, 0xF, 0xF, true));
  x += __int_as_float(__builtin_amdgcn_mov_dpp(__float_as_int(x), 0x140, 0xF, 0xF, true));
  return x;
}

// ---------------------------------------------------------------------------
// Precompute GEMM:  C[M][N] = A[M][0:512] * Bm[N][koff:koff+512]^T (+bias1+bias2)
// ---------------------------------------------------------------------------
__global__ __launch_bounds__(256) void gemm_nt_k512(
    const float* __restrict__ A, int M,
    const float* __restrict__ Bm, int ldb, int koff,
    const float* __restrict__ bias1, const float* __restrict__ bias2,
    float* __restrict__ C, int ldc)
{
  __shared__ float As[16][68];
  __shared__ float Bs[16][68];
  const int tid = threadIdx.x;
  const int m0 = blockIdx.y * 64, n0 = blockIdx.x * 64;
  const int tm = tid & 15, tn = tid >> 4;
  const int lm = tid & 63, kq = tid >> 6;
  float acc[4][4] = {};
  for (int k0 = 0; k0 < 512; k0 += 16) {
    float4 av = make_float4(0.f, 0.f, 0.f, 0.f);
    if (m0 + lm < M) av = *(const float4*)(A + (size_t)(m0 + lm) * 512 + k0 + kq * 4);
    float4 bv = *(const float4*)(Bm + (size_t)(n0 + lm) * ldb + koff + k0 + kq * 4);
    __syncthreads();
    As[kq*4+0][lm] = av.x; As[kq*4+1][lm] = av.y; As[kq*4+2][lm] = av.z; As[kq*4+3][lm] = av.w;
    Bs[kq*4+0][lm] = bv.x; Bs[kq*4+1][lm] = bv.y; Bs[kq*4+2][lm] = bv.z; Bs[kq*4+3][lm] = bv.w;
    __syncthreads();
#pragma unroll
    for (int kk = 0; kk < 16; ++kk) {
      const float4 a = *(const float4*)&As[kk][tm * 4];
      const float4 b = *(const float4*)&Bs[kk][tn * 4];
      const float aa[4] = {a.x, a.y, a.z, a.w};
      const float bb[4] = {b.x, b.y, b.z, b.w};
#pragma unroll
      for (int i = 0; i < 4; ++i)
#pragma unroll
        for (int j = 0; j < 4; ++j)
          acc[i][j] = fmaf(aa[i], bb[j], acc[i][j]);
    }
  }
#pragma unroll
  for (int i = 0; i < 4; ++i) {
    const int m = m0 + tm * 4 + i;
    if (m < M) {
#pragma unroll
      for (int j = 0; j < 4; ++j) {
        const int n = n0 + tn * 4 + j;
        float v = acc[i][j];
        if (bias1) v += bias1[n];
        if (bias2) v += bias2[n];
        C[(size_t)m * ldc + n] = v;
      }
    }
  }
}

// ---------------------------------------------------------------------------
// amax word: [val:f32 bits in high 32][tag:16][token:16]; tag(t) = t+2.
// ---------------------------------------------------------------------------
__global__ __launch_bounds__(256) void init_kernel(
    const float* __restrict__ ctx, float* __restrict__ hbuf,
    unsigned long long* __restrict__ amax,
    int* __restrict__ hdone, const int* __restrict__ start_id)
{
  const int i = blockIdx.x * blockDim.x + threadIdx.x;
  // h(-1) = context into slot 1
  ((float4*)(hbuf + B_ * H_))[i] = ((const float4*)ctx)[i];
  if (i < B_ * 32) {
    const int m = i & 31;
    const unsigned long long w = (m == 0)
        ? ((((unsigned long long)__float_as_uint(FLT_MAX)) << 32) |
           (1u << 16) | (unsigned)(*start_id))
        : ((((unsigned long long)__float_as_uint(-FLT_MAX)) << 32) | (1u << 16));
    amax[(size_t)B_ * 32 + i] = w;   // parity-1 slot, tag(-1)=1
  }
  if (i < 2 * 8 * 32) hdone[i * 16] = 0;
}

// ---------------------------------------------------------------------------
// Persistent cooperative decoder, 512 threads (8 waves, 2/SIMD, <=256 VGPR).
// 8 groups x 32 blocks; group g owns rows [16g,16g+16).  Tagged-dataflow sync.
//
//  * ONE merged h-pass per step: p2 logits(t) and p1 gates(t+1) both read the
//    same staged h(t) chunk -> 512 ds_read_b128/block/step (was 3072 in r1).
//  * Wave w = (blk = w&3 -> gate / vocab-octet, rg = w>>2 -> row parity):
//    lane (q1 = lane>>4, kc = lane&15) owns 4 gate-lines and 2 vocab rows,
//    K-chunk kc (32 floats).  Weights register-resident: 128+64 VGPR.
//  * Reductions over the 16 kc-lanes are 4 DPP adds (no LDS traffic).
//  * hs chunk stride 36 floats (144B): distinct-addr collisions are 2-way
//    (free, m136); same-addr across q1 groups broadcast.
//  * Fault-proofed: bounded spins + token clamp -> cannot hang, cannot OOB.
// ---------------------------------------------------------------------------
__global__ __launch_bounds__(512, 2) void decoder_main(
    const float* __restrict__ Whh,
    const float* __restrict__ Wout,
    const float* __restrict__ bout,
    const float* __restrict__ proj,
    const float* __restrict__ basep,
    float* __restrict__ hbuf,
    unsigned long long* __restrict__ amax,
    int* __restrict__ hdone,
    float* __restrict__ out)
{
  __shared__ struct alignas(16) SM {
    float hs[16][576];          // h tile, chunked: chunk kc at col kc*36, 32 floats
    float gbase[16][68];        // basep slice, loaded once
    float gbuf[16][68];         // gate accumulators [row][u*4+g]
    float lbuf[16][33];         // logits partials for argmax
    int   tok[16];
  } sm;

  const int tid  = threadIdx.x;
  const int bid  = blockIdx.x;
  const int gid  = bid >> 5;     // group: rows [16g, 16g+16)
  const int mem  = bid & 31;     // member: units [16*mem,+16) / vocab [32*mem,+32)
  const int lane = tid & 63;
  const int w    = tid >> 6;     // wave 0..7
  const int row_base = gid * 16;
  const int vb   = mem * 32;

  const int q1  = lane >> 4;     // 0..3
  const int kc  = lane & 15;     // K-chunk of 32 floats
  const int blk = w & 3;         // gate (p1) / vocab-octet (p2)
  const int rg  = w >> 2;        // row parity: rows rg+2s, s=0..7

  // ---- one-time preloads: weights -> registers ---------------------------
  float4 w1r[4][8];              // 4 gate-lines x 32 floats = 128 VGPR
#pragma unroll
  for (int i = 0; i < 4; ++i) {
    const float* p = Whh + (size_t)(blk * 512 + mem * 16 + q1 * 4 + i) * H_ + kc * 32;
#pragma unroll
    for (int j = 0; j < 8; ++j) w1r[i][j] = *(const float4*)(p + j * 4);
  }
  const int v0 = vb + blk * 8 + q1 * 2;
  const int v1 = v0 + 1;
  const int lv = blk * 8 + q1 * 2;
  float4 w2r[2][8];              // 2 vocab x 32 floats = 64 VGPR
#pragma unroll
  for (int i = 0; i < 2; ++i) {
    const int vv = (v0 + i < V_) ? (v0 + i) : (V_ - 1);
    const float* p = Wout + (size_t)vv * H_ + kc * 32;
#pragma unroll
    for (int j = 0; j < 8; ++j) w2r[i][j] = *(const float4*)(p + j * 4);
  }
  const float bo0 = bout[v0 < V_ ? v0 : V_ - 1];
  const float bo1 = bout[v1 < V_ ? v1 : V_ - 1];

  // basep slice -> LDS (2 elements/thread)
#pragma unroll
  for (int kx = 0; kx < 2; ++kx) {
    const int e = tid + kx * 512;
    const int r = e >> 6, c6 = e & 63, u = c6 & 15, g = c6 >> 4;
    sm.gbase[r][u * 4 + g] =
        basep[(size_t)(row_base + r) * G4_ + mem * 16 + u + g * 512];
  }

  float c_reg = 0.f;   // tid<256 owns cell (row=row_base+(tid>>4), unit=mem*16+(tid&15))
  const size_t BTVo = (size_t)B_ * T_ * V_;

  // ---- prepass: stage h(-1)=context, fill gbuf = Whh*h(-1)+basep ---------
  {
    const float* hsrc = hbuf + (size_t)B_ * H_;   // slot 1 = context
    const unsigned long long* hq =
        (const unsigned long long*)(hsrc + (size_t)row_base * H_);
    unsigned long long v[8];
#pragma unroll
    for (int i = 0; i < 8; ++i) v[i] = AT_LOAD(&hq[tid + i * 512]);
    __syncthreads();   // gbase writes land before any hs reader
#pragma unroll
    for (int i = 0; i < 8; ++i) {
      const int idx2 = tid + i * 512;
      const int row = idx2 >> 8, cp = idx2 & 255;
      *(unsigned long long*)&sm.hs[row][(cp >> 4) * 36 + (cp & 15) * 2] = v[i];
    }
  }
  __syncthreads();
#pragma unroll 1
  for (int s = 0; s < 8; ++s) {
    const int r = rg + 2 * s;
    const float* hr = &sm.hs[r][kc * 36];
    float a0 = 0.f, a1 = 0.f, a2 = 0.f, a3 = 0.f;
    float4 hv[4];
#pragma unroll
    for (int half = 0; half < 2; ++half) {
#pragma unroll
      for (int j = 0; j < 4; ++j) hv[j] = *(const float4*)(hr + half * 16 + j * 4);
#pragma unroll
      for (int j = 0; j < 4; ++j) {
        a0 = dot4(w1r[0][half * 4 + j], hv[j], a0);
        a1 = dot4(w1r[1][half * 4 + j], hv[j], a1);
        a2 = dot4(w1r[2][half * 4 + j], hv[j], a2);
        a3 = dot4(w1r[3][half * 4 + j], hv[j], a3);
      }
    }
    a0 = red16(a0); a1 = red16(a1); a2 = red16(a2); a3 = red16(a3);
    if (kc == 0) { const int u = q1 * 4 + 0; sm.gbuf[r][u * 4 + blk] = a0 + sm.gbase[r][u * 4 + blk]; }
    if (kc == 1) { const int u = q1 * 4 + 1; sm.gbuf[r][u * 4 + blk] = a1 + sm.gbase[r][u * 4 + blk]; }
    if (kc == 2) { const int u = q1 * 4 + 2; sm.gbuf[r][u * 4 + blk] = a2 + sm.gbase[r][u * 4 + blk]; }
    if (kc == 3) { const int u = q1 * 4 + 3; sm.gbuf[r][u * 4 + blk] = a3 + sm.gbase[r][u * 4 + blk]; }
  }
  __syncthreads();

  for (int t = 0; t < T_; ++t) {
    float* hdst = hbuf + (size_t)(t & 1) * (B_ * H_);

    // ---- B: poll amax(t-1) -> tok[] -------------------------------------
    {
      const int prow = tid >> 5, pj = tid & 31;
      const unsigned expect = (unsigned)(t + 1) << 16;   // tag(t-1) = t+1
      const unsigned long long* ap =
          amax + ((size_t)((t + 1) & 1) * B_ + row_base + prow) * 32;
      unsigned long long wv = AT_LOAD(&ap[pj]);
      for (int it = 0; (((unsigned)wv ^ expect) & 0xFFFF0000u) && it < SPIN_MAX; ++it) {
        __builtin_amdgcn_s_sleep(1);
        wv = AT_LOAD(&ap[pj]);
      }
      __atomic_signal_fence(__ATOMIC_ACQ_REL);
      float v  = __uint_as_float((unsigned)(wv >> 32));
      int   ix = (int)((unsigned)wv & 0xFFFFu);
#pragma unroll
      for (int d = 16; d >= 1; d >>= 1) {
        const float vo = __shfl_xor(v, d, 32);
        const int   io = __shfl_xor(ix, d, 32);
        if (vo > v || (vo == v && io < ix)) { v = vo; ix = io; }
      }
      if (pj == 0) sm.tok[prow] = (ix < V_ && ix >= 0) ? ix : 0;  // clamp: no OOB ever
    }
    __syncthreads();

    // ---- C: add proj[token] into gbuf (2 elements per thread) ------------
#pragma unroll
    for (int kx = 0; kx < 2; ++kx) {
      const int e = tid + kx * 512;
      const int r = e >> 6, c6 = e & 63, u = c6 & 15, g = c6 >> 4;
      const int tk = sm.tok[r];
      sm.gbuf[r][u * 4 + g] += proj[(size_t)tk * G4_ + mem * 16 + u + g * 512];
    }
    __syncthreads();

    // ---- D: LSTM epilogue (tid<256): c in register ----------------------
    if (tid < 256) {
      const int rl = tid >> 4, ul = tid & 15;
      const float4 g4 = *(const float4*)&sm.gbuf[rl][ul * 4];
      const float ig = 1.f / (1.f + expf(-g4.x));
      const float fg = 1.f / (1.f + expf(-g4.y));
      const float gg = tanhf(g4.z);
      const float og = 1.f / (1.f + expf(-g4.w));
      const float cn = fg * c_reg + ig * gg;
      c_reg = cn;
      const float hn = og * tanhf(cn);
      const int row = row_base + rl, hid = mem * 16 + ul;
      const float hn2 = __shfl_down(hn, 1);
      if ((ul & 1) == 0) {
        const unsigned long long pk =
            (unsigned long long)__float_as_uint(hn) |
            (((unsigned long long)__float_as_uint(hn2)) << 32);
        AT_STORE((unsigned long long*)&hdst[(size_t)row * H_ + hid], pk);
      }
      if (t == T_ - 1) {
        out[BTVo + (size_t)row * H_ + hid] = hn;                    // h_f
        out[BTVo + (size_t)B_ * H_ + (size_t)row * H_ + hid] = cn;  // c_f
      }
    }
    __syncthreads();   // drains vmcnt -> release for hdone flag
    if (tid == 0)
      AT_STORE(&hdone[(((t & 1) * 8 + gid) * 32 + mem) * 16], t + 2);

    // ---- E: wait for all members' h(t) ----------------------------------
    if (tid < 32) {
      int* fp = &hdone[(((t & 1) * 8 + gid) * 32 + tid) * 16];
      for (int it = 0; AT_LOAD(fp) != t + 2 && it < SPIN_MAX; ++it)
        __builtin_amdgcn_s_sleep(1);
    }
    __atomic_signal_fence(__ATOMIC_ACQ_REL);
    __syncthreads();

    // ---- F: stage h(t) into hs (chunked stride 36) ----------------------
    {
      const unsigned long long* hq =
          (const unsigned long long*)(hdst + (size_t)row_base * H_);
      unsigned long long v[8];
#pragma unroll
      for (int i = 0; i < 8; ++i) v[i] = AT_LOAD(&hq[tid + i * 512]);
#pragma unroll
      for (int i = 0; i < 8; ++i) {
        const int idx2 = tid + i * 512;
        const int row = idx2 >> 8, cp = idx2 & 255;
        *(unsigned long long*)&sm.hs[row][(cp >> 4) * 36 + (cp & 15) * 2] = v[i];
      }
    }
    __syncthreads();

    // ---- MERGED: p2 logits(t) + p1 gates(t+1), one h read ---------------
#pragma unroll 1
    for (int s = 0; s < 8; ++s) {
      const int r = rg + 2 * s;
      const float* hr = &sm.hs[r][kc * 36];
      float a0 = 0.f, a1 = 0.f, a2 = 0.f, a3 = 0.f, b0 = 0.f, b1 = 0.f;
      float4 hv[4];
#pragma unroll
      for (int half = 0; half < 2; ++half) {
#pragma unroll
        for (int j = 0; j < 4; ++j) hv[j] = *(const float4*)(hr + half * 16 + j * 4);
#pragma unroll
        for (int j = 0; j < 4; ++j) {
          a0 = dot4(w1r[0][half * 4 + j], hv[j], a0);
          a1 = dot4(w1r[1][half * 4 + j], hv[j], a1);
          a2 = dot4(w1r[2][half * 4 + j], hv[j], a2);
          a3 = dot4(w1r[3][half * 4 + j], hv[j], a3);
          b0 = dot4(w2r[0][half * 4 + j], hv[j], b0);
          b1 = dot4(w2r[1][half * 4 + j], hv[j], b1);
        }
      }
      a0 = red16(a0); a1 = red16(a1); a2 = red16(a2); a3 = red16(a3);
      b0 = red16(b0); b1 = red16(b1);
      if (kc == 0) { const int u = q1 * 4 + 0; sm.gbuf[r][u * 4 + blk] = a0 + sm.gbase[r][u * 4 + blk]; }
      if (kc == 1) { const int u = q1 * 4 + 1; sm.gbuf[r][u * 4 + blk] = a1 + sm.gbase[r][u * 4 + blk]; }
      if (kc == 2) { const int u = q1 * 4 + 2; sm.gbuf[r][u * 4 + blk] = a2 + sm.gbase[r][u * 4 + blk]; }
      if (kc == 3) { const int u = q1 * 4 + 3; sm.gbuf[r][u * 4 + blk] = a3 + sm.gbase[r][u * 4 + blk]; }
      if (kc == 8) {
        const size_t ob = ((size_t)(row_base + r) * T_ + t) * V_;
        if (v0 < V_) {
          const float s0 = b0 + bo0;
          out[ob + v0] = s0; sm.lbuf[r][lv] = s0;
        } else sm.lbuf[r][lv] = -FLT_MAX;
        if (v1 < V_) {
          const float s1 = b1 + bo1;
          out[ob + v1] = s1; sm.lbuf[r][lv + 1] = s1;
        } else sm.lbuf[r][lv + 1] = -FLT_MAX;
      }
    }
    __syncthreads();

    // ---- H: per-member argmax partial -----------------------------------
    {
      const int r = tid >> 5, j = tid & 31;
      float v = sm.lbuf[r][j];
      int ix = j;
#pragma unroll
      for (int d = 16; d >= 1; d >>= 1) {
        const float vo = __shfl_xor(v, d, 32);
        const int   io = __shfl_xor(ix, d, 32);
        if (vo > v || (vo == v && io < ix)) { v = vo; ix = io; }
      }
      if (j == 0) {
        const unsigned long long pk =
            (((unsigned long long)__float_as_uint(v)) << 32) |
            ((unsigned)(t + 2) << 16) | (unsigned)(vb + ix);
        AT_STORE(&amax[((size_t)(t & 1) * B_ + row_base + r) * 32 + mem], pk);
      }
    }
    // no barrier: loop back (B polls global amax; lbuf rewritten only after
    // next iteration's F barrier chain)
  }
}

// ---------------------------------------------------------------------------
extern "C" void kernel_launch(void* const* d_in, const int* in_sizes, int n_in,
                              void* d_out, int out_size, void* d_ws, size_t ws_size,
                              hipStream_t stream)
{
  const float* ctx   = (const float*)d_in[0];
  const float* emb   = (const float*)d_in[1];
  const float* Wih   = (const float*)d_in[2];
  const float* bih   = (const float*)d_in[3];
  const float* Whh   = (const float*)d_in[4];
  const float* bhh   = (const float*)d_in[5];
  const float* Wout  = (const float*)d_in[6];
  const float* bout  = (const float*)d_in[7];
  const int*   start = (const int*)d_in[8];
  float* out = (float*)d_out;

  // workspace layout (bytes)
  char* ws = (char*)d_ws;
  float* proj  = (float*)(ws + 0);                    // 1000*2048*4 = 8,192,000
  float* basep = (float*)(ws + 8192000);              // 128*2048*4  = 1,048,576
  float* hbuf  = (float*)(ws + 9240576);              // 2*128*512*4 =   524,288
  unsigned long long* amax = (unsigned long long*)(ws + 9764864);  // 2*128*32*8 = 65,536
  int*   hdone = (int*)(ws + 9830400);                // 2*8*32*64B  =    32,768

  hipLaunchKernelGGL(gemm_nt_k512, dim3(32, 2), dim3(256), 0, stream,
                     ctx, B_, Wih, 1024, 0, bih, bhh, basep, G4_);
  hipLaunchKernelGGL(gemm_nt_k512, dim3(32, 16), dim3(256), 0, stream,
                     emb, V_, Wih, 1024, 512, (const float*)nullptr, (const float*)nullptr,
                     proj, G4_);
  hipLaunchKernelGGL(init_kernel, dim3(64), dim3(256), 0, stream,
                     ctx, hbuf, amax, hdone, start);

  void* args[] = {(void*)&Whh, (void*)&Wout, (void*)&bout, (void*)&proj, (void*)&basep,
                  (void*)&hbuf, (void*)&amax, (void*)&hdone, (void*)&out};
  hipLaunchCooperativeKernel(reinterpret_cast<const void*>(decoder_main),
                             dim3(NBLK), dim3(512), args, 0, stream);
}

// Round 5
// 3424.208 us; speedup vs baseline: 2.2091x; 1.2534x over previous
//
#include <hip/hip_runtime.h>
#include <float.h>
#include <math.h>

#define B_    128
#define H_    512
#define V_    1000
#define T_    256
#define G4_   2048
#define NBLK  256          // cooperative launch: 1 block/CU
#define SPIN_MAX (1 << 17) // bounded spin: converts would-be hang into wrong-answer

#define AT_LOAD(p)    __hip_atomic_load((p), __ATOMIC_RELAXED, __HIP_MEMORY_SCOPE_AGENT)
#define AT_STORE(p,v) __hip_atomic_store((p), (v), __ATOMIC_RELAXED, __HIP_MEMORY_SCOPE_AGENT)

__device__ __forceinline__ float dot4(float4 a, float4 b, float acc) {
  return fmaf(a.x, b.x, fmaf(a.y, b.y, fmaf(a.z, b.z, fmaf(a.w, b.w, acc))));
}

// 16-lane butterfly sum, pure DPP (VALU pipe, zero LDS traffic).
__device__ __forceinline__ float red16(float x) {
  x += __int_as_float(__builtin_amdgcn_mov_dpp(__float_as_int(x), 0xB1,  0xF, 0xF, true));
  x += __int_as_float(__builtin_amdgcn_mov_dpp(__float_as_int(x), 0x4E,  0xF, 0xF, true));
  x += __int_as_float(__builtin_amdgcn_mov_dpp(__float_as_int(x), 0x141, 0xF, 0xF, true));
  x += __int_as_float(__builtin_amdgcn_mov_dpp(__float_as_int(x), 0x140, 0xF, 0xF, true));
  return x;
}

// ---------------------------------------------------------------------------
// Precompute GEMM:  C = A[M][0:512] * Bm[N][koff:+512]^T (+bias1+bias2).
// ileave=1 stores gate-interleaved: C[m][ (n&511)*4 + (n>>9) ]  (ldc=2048),
// so the decoder reads all 4 gates of one unit as a single float4.
// ---------------------------------------------------------------------------
__global__ __launch_bounds__(256) void gemm_nt_k512(
    const float* __restrict__ A, int M,
    const float* __restrict__ Bm, int ldb, int koff,
    const float* __restrict__ bias1, const float* __restrict__ bias2,
    float* __restrict__ C, int ldc, int ileave)
{
  __shared__ float As[16][68];
  __shared__ float Bs[16][68];
  const int tid = threadIdx.x;
  const int m0 = blockIdx.y * 64, n0 = blockIdx.x * 64;
  const int tm = tid & 15, tn = tid >> 4;
  const int lm = tid & 63, kq = tid >> 6;
  float acc[4][4] = {};
  for (int k0 = 0; k0 < 512; k0 += 16) {
    float4 av = make_float4(0.f, 0.f, 0.f, 0.f);
    if (m0 + lm < M) av = *(const float4*)(A + (size_t)(m0 + lm) * 512 + k0 + kq * 4);
    float4 bv = *(const float4*)(Bm + (size_t)(n0 + lm) * ldb + koff + k0 + kq * 4);
    __syncthreads();
    As[kq*4+0][lm] = av.x; As[kq*4+1][lm] = av.y; As[kq*4+2][lm] = av.z; As[kq*4+3][lm] = av.w;
    Bs[kq*4+0][lm] = bv.x; Bs[kq*4+1][lm] = bv.y; Bs[kq*4+2][lm] = bv.z; Bs[kq*4+3][lm] = bv.w;
    __syncthreads();
#pragma unroll
    for (int kk = 0; kk < 16; ++kk) {
      const float4 a = *(const float4*)&As[kk][tm * 4];
      const float4 b = *(const float4*)&Bs[kk][tn * 4];
      const float aa[4] = {a.x, a.y, a.z, a.w};
      const float bb[4] = {b.x, b.y, b.z, b.w};
#pragma unroll
      for (int i = 0; i < 4; ++i)
#pragma unroll
        for (int j = 0; j < 4; ++j)
          acc[i][j] = fmaf(aa[i], bb[j], acc[i][j]);
    }
  }
#pragma unroll
  for (int i = 0; i < 4; ++i) {
    const int m = m0 + tm * 4 + i;
    if (m < M) {
#pragma unroll
      for (int j = 0; j < 4; ++j) {
        const int n = n0 + tn * 4 + j;
        float v = acc[i][j];
        if (bias1) v += bias1[n];
        if (bias2) v += bias2[n];
        const size_t idx = ileave ? ((size_t)m * ldc + (size_t)(n & 511) * 4 + (n >> 9))
                                  : ((size_t)m * ldc + n);
        C[idx] = v;
      }
    }
  }
}

// ---------------------------------------------------------------------------
// amax word: [val:f32 bits in high 32][tag:16][token:16]; tag(t) = t+2.
// ---------------------------------------------------------------------------
__global__ __launch_bounds__(256) void init_kernel(
    const float* __restrict__ ctx, float* __restrict__ hbuf,
    unsigned long long* __restrict__ amax,
    int* __restrict__ hdone, const int* __restrict__ start_id)
{
  const int i = blockIdx.x * blockDim.x + threadIdx.x;
  // h(-1) = context into slot 1
  ((float4*)(hbuf + B_ * H_))[i] = ((const float4*)ctx)[i];
  if (i < B_ * 32) {
    const int m = i & 31;
    const unsigned long long w = (m == 0)
        ? ((((unsigned long long)__float_as_uint(FLT_MAX)) << 32) |
           (1u << 16) | (unsigned)(*start_id))
        : ((((unsigned long long)__float_as_uint(-FLT_MAX)) << 32) | (1u << 16));
    amax[(size_t)B_ * 32 + i] = w;   // parity-1 slot, tag(-1)=1
  }
  if (i < 2 * 8 * 32) hdone[i * 16] = 0;
}

// ---------------------------------------------------------------------------
// Persistent cooperative decoder, 512 threads (8 waves, 2/SIMD).
// 8 groups x 32 blocks; group g owns rows [16g,16g+16).  Tagged-dataflow sync.
//
// Round-5 structure:
//  * K-PARITY SPLIT: wave w -> (blk = w&3, par = w>>2).  Waves blk/blk+4 own
//    the SAME 4 gate-lines + 2 vocab rows but different 256-float K-halves.
//    Per-lane weights: w1r 4x4 float4 (64) + w2r 2x4 float4 (32) = 96 VGPR,
//    zero duplication -> genuinely register-resident (r4 spilled at 192).
//    Cross-parity combine via gbuf2[2]/lbuf2[2] LDS planes, summed in D/H.
//  * hs is LINEAR [16][512]: 16-float K-chunks per lane -> distinct 16B
//    slots per kc, q1-groups broadcast -> conflict-free without swizzle.
//  * Loop order p1 -> B -> D -> exchange -> p2 -> H: amax(t-1) propagation
//    hides under the p1 GEMM (~2us); phase C eliminated (proj/basep stored
//    gate-interleaved, D adds proj as one coalesced float4).
//  * Fault-proofed: bounded spins + token clamp (no hang, no OOB).
// ---------------------------------------------------------------------------
__global__ __launch_bounds__(512, 2) void decoder_main(
    const float* __restrict__ Whh,
    const float* __restrict__ Wout,
    const float* __restrict__ bout,
    const float* __restrict__ proj,
    const float* __restrict__ basep,
    float* __restrict__ hbuf,
    unsigned long long* __restrict__ amax,
    int* __restrict__ hdone,
    float* __restrict__ out)
{
  __shared__ struct alignas(16) SM {
    float hs[16][512];          // h tile, linear
    float gbase[16][68];        // interleaved basep slice [r][u*4+g]
    float gbuf2[2][16][68];     // gate partials per K-parity
    float lbuf2[2][16][34];     // logit partials per K-parity
    float sbout[32];
    int   tok[16];
  } sm;

  const int tid  = threadIdx.x;
  const int bid  = blockIdx.x;
  const int gid  = bid >> 5;     // group: rows [16g, 16g+16)
  const int mem  = bid & 31;     // member: units [16*mem,+16) / vocab [32*mem,+32)
  const int lane = tid & 63;
  const int w    = tid >> 6;     // wave 0..7
  const int row_base = gid * 16;
  const int vb   = mem * 32;

  const int q1  = lane >> 4;     // 0..3
  const int kc  = lane & 15;     // 16-float K-chunk within the K-half
  const int blk = w & 3;         // gate-line block / vocab-octet
  const int par = w >> 2;        // K-half 0/1
  const int hoff = par * 256 + kc * 16;

  // ---- one-time preloads: weights -> registers (96 VGPR, no duplication) --
  float4 w1r[4][4];              // 4 gate-lines x 16 floats
#pragma unroll
  for (int i = 0; i < 4; ++i) {
    const float* p = Whh + (size_t)(blk * 512 + mem * 16 + q1 * 4 + i) * H_ + hoff;
#pragma unroll
    for (int j = 0; j < 4; ++j) w1r[i][j] = *(const float4*)(p + j * 4);
  }
  const int v0 = vb + blk * 8 + q1 * 2;
  float4 w2r[2][4];              // 2 vocab x 16 floats
#pragma unroll
  for (int jj = 0; jj < 2; ++jj) {
    const int vv = (v0 + jj < V_) ? (v0 + jj) : (V_ - 1);
    const float* p = Wout + (size_t)vv * H_ + hoff;
#pragma unroll
    for (int j = 0; j < 4; ++j) w2r[jj][j] = *(const float4*)(p + j * 4);
  }

  // basep slice (interleaved) -> LDS; bout slice -> LDS
#pragma unroll
  for (int kx = 0; kx < 2; ++kx) {
    const int e = tid + kx * 512;
    const int r = e >> 6, c = e & 63;
    sm.gbase[r][c] = basep[(size_t)(row_base + r) * G4_ + mem * 64 + c];
  }
  if (tid < 32) sm.sbout[tid] = (vb + tid < V_) ? bout[vb + tid] : 0.f;

  float c_reg = 0.f;   // tid<256 owns cell (row=row_base+(tid>>4), unit=mem*16+(tid&15))
  const size_t BTVo = (size_t)B_ * T_ * V_;

  // ---- prepass: stage h(-1)=context into hs (linear) ---------------------
  {
    const unsigned long long* hq =
        (const unsigned long long*)(hbuf + (size_t)B_ * H_ + (size_t)row_base * H_);
    unsigned long long v[8];
#pragma unroll
    for (int i = 0; i < 8; ++i) v[i] = AT_LOAD(&hq[tid + i * 512]);
#pragma unroll
    for (int i = 0; i < 8; ++i) {
      const int idx = tid + i * 512;
      *(unsigned long long*)&sm.hs[idx >> 8][(idx & 255) * 2] = v[i];
    }
  }
  __syncthreads();

  for (int t = 0; t < T_; ++t) {
    float* hdst = hbuf + (size_t)(t & 1) * (B_ * H_);

    // ---- P1: gates(t) partials = Whh_half * h(t-1) -> gbuf2[par] ---------
#pragma unroll 1
    for (int r = 0; r < 16; ++r) {
      const float* hr = &sm.hs[r][hoff];
      const float4 h0 = *(const float4*)(hr + 0);
      const float4 h1 = *(const float4*)(hr + 4);
      const float4 h2 = *(const float4*)(hr + 8);
      const float4 h3 = *(const float4*)(hr + 12);
      float a0 = dot4(w1r[0][3], h3, dot4(w1r[0][2], h2, dot4(w1r[0][1], h1, dot4(w1r[0][0], h0, 0.f))));
      float a1 = dot4(w1r[1][3], h3, dot4(w1r[1][2], h2, dot4(w1r[1][1], h1, dot4(w1r[1][0], h0, 0.f))));
      float a2 = dot4(w1r[2][3], h3, dot4(w1r[2][2], h2, dot4(w1r[2][1], h1, dot4(w1r[2][0], h0, 0.f))));
      float a3 = dot4(w1r[3][3], h3, dot4(w1r[3][2], h2, dot4(w1r[3][1], h1, dot4(w1r[3][0], h0, 0.f))));
      a0 = red16(a0); a1 = red16(a1); a2 = red16(a2); a3 = red16(a3);
      if (kc < 4) {
        const float av = (kc == 0) ? a0 : (kc == 1) ? a1 : (kc == 2) ? a2 : a3;
        sm.gbuf2[par][r][(q1 * 4 + kc) * 4 + blk] = av;
      }
    }

    // ---- B: poll amax(t-1) -> tok[]  (propagation hidden under P1) ------
    {
      const int prow = tid >> 5, pj = tid & 31;
      const unsigned expect = (unsigned)(t + 1) << 16;   // tag(t-1) = t+1
      const unsigned long long* ap =
          amax + ((size_t)((t + 1) & 1) * B_ + row_base + prow) * 32;
      unsigned long long wv = AT_LOAD(&ap[pj]);
      for (int it = 0; (((unsigned)wv ^ expect) & 0xFFFF0000u) && it < SPIN_MAX; ++it) {
        __builtin_amdgcn_s_sleep(1);
        wv = AT_LOAD(&ap[pj]);
      }
      __atomic_signal_fence(__ATOMIC_ACQ_REL);
      float v  = __uint_as_float((unsigned)(wv >> 32));
      int   ix = (int)((unsigned)wv & 0xFFFFu);
#pragma unroll
      for (int d = 16; d >= 1; d >>= 1) {
        const float vo = __shfl_xor(v, d, 32);
        const int   io = __shfl_xor(ix, d, 32);
        if (vo > v || (vo == v && io < ix)) { v = vo; ix = io; }
      }
      if (pj == 0) sm.tok[prow] = (ix >= 0 && ix < V_) ? ix : 0;   // clamp
    }
    __syncthreads();

    // ---- D: LSTM epilogue (tid<256): combine parities + proj + gbase ----
    if (tid < 256) {
      const int rl = tid >> 4, ul = tid & 15;
      const int tk = sm.tok[rl];
      const float4 ga = *(const float4*)&sm.gbuf2[0][rl][ul * 4];
      const float4 gb = *(const float4*)&sm.gbuf2[1][rl][ul * 4];
      const float4 gc = *(const float4*)&sm.gbase[rl][ul * 4];
      const float4 gp = *(const float4*)&proj[(size_t)tk * G4_ + (size_t)(mem * 16 + ul) * 4];
      const float gx = ga.x + gb.x + gc.x + gp.x;
      const float gy = ga.y + gb.y + gc.y + gp.y;
      const float gz = ga.z + gb.z + gc.z + gp.z;
      const float gw = ga.w + gb.w + gc.w + gp.w;
      const float ig = 1.f / (1.f + expf(-gx));
      const float fg = 1.f / (1.f + expf(-gy));
      const float gg = tanhf(gz);
      const float og = 1.f / (1.f + expf(-gw));
      const float cn = fg * c_reg + ig * gg;
      c_reg = cn;
      const float hn = og * tanhf(cn);
      const int row = row_base + rl, hid = mem * 16 + ul;
      const float hn2 = __shfl_down(hn, 1);
      if ((ul & 1) == 0) {
        const unsigned long long pk =
            (unsigned long long)__float_as_uint(hn) |
            (((unsigned long long)__float_as_uint(hn2)) << 32);
        AT_STORE((unsigned long long*)&hdst[(size_t)row * H_ + hid], pk);
      }
      if (t == T_ - 1) {
        out[BTVo + (size_t)row * H_ + hid] = hn;                    // h_f
        out[BTVo + (size_t)B_ * H_ + (size_t)row * H_ + hid] = cn;  // c_f
      }
    }
    __syncthreads();   // drains vmcnt -> release for hdone flag
    if (tid == 0)
      AT_STORE(&hdone[(((t & 1) * 8 + gid) * 32 + mem) * 16], t + 2);

    // ---- E: wait for all members' h(t) ----------------------------------
    if (tid < 32) {
      int* fp = &hdone[(((t & 1) * 8 + gid) * 32 + tid) * 16];
      for (int it = 0; AT_LOAD(fp) != t + 2 && it < SPIN_MAX; ++it)
        __builtin_amdgcn_s_sleep(1);
    }
    __atomic_signal_fence(__ATOMIC_ACQ_REL);
    __syncthreads();

    // ---- F: stage h(t) into hs (linear) ---------------------------------
    {
      const unsigned long long* hq =
          (const unsigned long long*)(hdst + (size_t)row_base * H_);
      unsigned long long v[8];
#pragma unroll
      for (int i = 0; i < 8; ++i) v[i] = AT_LOAD(&hq[tid + i * 512]);
#pragma unroll
      for (int i = 0; i < 8; ++i) {
        const int idx = tid + i * 512;
        *(unsigned long long*)&sm.hs[idx >> 8][(idx & 255) * 2] = v[i];
      }
    }
    __syncthreads();

    // ---- P2: logits(t) partials = Wout_half * h(t) -> lbuf2[par] --------
#pragma unroll 1
    for (int r = 0; r < 16; ++r) {
      const float* hr = &sm.hs[r][hoff];
      const float4 h0 = *(const float4*)(hr + 0);
      const float4 h1 = *(const float4*)(hr + 4);
      const float4 h2 = *(const float4*)(hr + 8);
      const float4 h3 = *(const float4*)(hr + 12);
      float b0 = dot4(w2r[0][3], h3, dot4(w2r[0][2], h2, dot4(w2r[0][1], h1, dot4(w2r[0][0], h0, 0.f))));
      float b1 = dot4(w2r[1][3], h3, dot4(w2r[1][2], h2, dot4(w2r[1][1], h1, dot4(w2r[1][0], h0, 0.f))));
      b0 = red16(b0); b1 = red16(b1);
      if (kc < 2)
        sm.lbuf2[par][r][blk * 8 + q1 * 2 + kc] = (kc == 0) ? b0 : b1;
    }
    __syncthreads();

    // ---- H: combine parities, write logits, argmax -> amax --------------
    {
      const int r = tid >> 5, j = tid & 31;
      float v = sm.lbuf2[0][r][j] + sm.lbuf2[1][r][j] + sm.sbout[j];
      if (vb + j < V_)
        out[((size_t)(row_base + r) * T_ + t) * V_ + vb + j] = v;
      else
        v = -FLT_MAX;
      int ix = j;
#pragma unroll
      for (int d = 16; d >= 1; d >>= 1) {
        const float vo = __shfl_xor(v, d, 32);
        const int   io = __shfl_xor(ix, d, 32);
        if (vo > v || (vo == v && io < ix)) { v = vo; ix = io; }
      }
      if (j == 0) {
        const unsigned long long pk =
            (((unsigned long long)__float_as_uint(v)) << 32) |
            ((unsigned)(t + 2) << 16) | (unsigned)(vb + ix);
        AT_STORE(&amax[((size_t)(t & 1) * B_ + row_base + r) * 32 + mem], pk);
      }
    }
    // no barrier: next iteration's P1 reads hs (stable until next F) and
    // writes gbuf2 (disjoint from lbuf2/out/amax used in H).
  }
}

// ---------------------------------------------------------------------------
extern "C" void kernel_launch(void* const* d_in, const int* in_sizes, int n_in,
                              void* d_out, int out_size, void* d_ws, size_t ws_size,
                              hipStream_t stream)
{
  const float* ctx   = (const float*)d_in[0];
  const float* emb   = (const float*)d_in[1];
  const float* Wih   = (const float*)d_in[2];
  const float* bih   = (const float*)d_in[3];
  const float* Whh   = (const float*)d_in[4];
  const float* bhh   = (const float*)d_in[5];
  const float* Wout  = (const float*)d_in[6];
  const float* bout  = (const float*)d_in[7];
  const int*   start = (const int*)d_in[8];
  float* out = (float*)d_out;

  // workspace layout (bytes)
  char* ws = (char*)d_ws;
  float* proj  = (float*)(ws + 0);                    // 1000*2048*4 = 8,192,000
  float* basep = (float*)(ws + 8192000);              // 128*2048*4  = 1,048,576
  float* hbuf  = (float*)(ws + 9240576);              // 2*128*512*4 =   524,288
  unsigned long long* amax = (unsigned long long*)(ws + 9764864);  // 2*128*32*8 = 65,536
  int*   hdone = (int*)(ws + 9830400);                // 2*8*32*64B  =    32,768

  hipLaunchKernelGGL(gemm_nt_k512, dim3(32, 2), dim3(256), 0, stream,
                     ctx, B_, Wih, 1024, 0, bih, bhh, basep, G4_, 1);
  hipLaunchKernelGGL(gemm_nt_k512, dim3(32, 16), dim3(256), 0, stream,
                     emb, V_, Wih, 1024, 512, (const float*)nullptr, (const float*)nullptr,
                     proj, G4_, 1);
  hipLaunchKernelGGL(init_kernel, dim3(64), dim3(256), 0, stream,
                     ctx, hbuf, amax, hdone, start);

  void* args[] = {(void*)&Whh, (void*)&Wout, (void*)&bout, (void*)&proj, (void*)&basep,
                  (void*)&hbuf, (void*)&amax, (void*)&hdone, (void*)&out};
  hipLaunchCooperativeKernel(reinterpret_cast<const void*>(decoder_main),
                             dim3(NBLK), dim3(512), args, 0, stream);
}